// Round 3
// baseline (256.066 us; speedup 1.0000x reference)
//
#include <hip/hip_runtime.h>
#include <hip/hip_bf16.h>
#include <stdint.h>

typedef unsigned short u16;
typedef short s16x8 __attribute__((ext_vector_type(8)));
typedef float f32x4 __attribute__((ext_vector_type(4)));
typedef unsigned short u16x4 __attribute__((ext_vector_type(4)));

#define GLL(gp, lp) __builtin_amdgcn_global_load_lds( \
    (const __attribute__((address_space(1))) void*)(gp), \
    (__attribute__((address_space(3))) void*)(lp), 16, 0, 0)

// ---------------- exact-math helpers (match XLA/np f32 semantics) -----------

__device__ __forceinline__ float xla_erf(float x) {
#pragma clang fp contract(off)
  x = fminf(3.832506856900711f, fmaxf(-3.832506856900711f, x));
  float x2 = x * x;
  float p = -2.72614225801306e-10f;
  p = p * x2 + 2.77068142495902e-08f;
  p = p * x2 + -2.10102402082508e-06f;
  p = p * x2 + -5.69250639462346e-05f;
  p = p * x2 + -7.34990630326855e-04f;
  p = p * x2 + -2.95459980854025e-03f;
  p = p * x2 + -1.60960333262415e-02f;
  p = x * p;
  float q = -1.45660718464996e-05f;
  q = q * x2 + -2.13374055278905e-04f;
  q = q * x2 + -1.68282697438203e-03f;
  q = q * x2 + -7.37332916720468e-03f;
  q = q * x2 + -1.42647390514189e-02f;
  return p / q;
}

__device__ __forceinline__ float gelu_exact(float x) {
#pragma clang fp contract(off)
  float t = x / 1.41421356237309504880f;
  float e = xla_erf(t);
  float u = e + 1.0f;
  float v = x * u;
  return v * 0.5f;
}

__device__ __forceinline__ float epi_scale(float iacc, float sc, float b) {
#pragma clang fp contract(off)
  float v = iacc * sc;
  v = v + b;
  return v;
}

__device__ __forceinline__ int quant1(float x, float scale) {
#pragma clang fp contract(off)
  float t = x / scale;
  t = rintf(t);
  t = fmaxf(-8.0f, fminf(7.0f, t));
  return (int)t;
}

// ---------------- small kernels ---------------------------------------------

__global__ void init_kernel(unsigned* slots) {
  if (threadIdx.x < 4) slots[threadIdx.x] = 0u;
}

__global__ void absmax3(const float* __restrict__ p0, long n0,
                        const float* __restrict__ p1, long n1,
                        const float* __restrict__ p2, long n2,
                        unsigned* __restrict__ slots) {
  const int t = blockIdx.y;
  const float4* p = (const float4*)(t == 0 ? p0 : (t == 1 ? p1 : p2));
  const long n4 = (t == 0 ? n0 : (t == 1 ? n1 : n2));
  float m = 0.0f;
  long i = (long)blockIdx.x * blockDim.x + threadIdx.x;
  const long stride = (long)gridDim.x * blockDim.x;
  for (; i < n4; i += stride) {
    float4 v = p[i];
    m = fmaxf(m, fmaxf(fmaxf(fabsf(v.x), fabsf(v.y)), fmaxf(fabsf(v.z), fabsf(v.w))));
  }
  for (int o = 32; o > 0; o >>= 1) m = fmaxf(m, __shfl_xor(m, o));
  if ((threadIdx.x & 63) == 0) atomicMax(slots + t, __float_as_uint(m));
}

// fp32 [R][C] -> bf16-int [Rpad][ldq], ldq = C + 32; extra columns hold the
// per-segment signed AND-mask (ADC correction; sign=-1 for weights), zero-pad.
__global__ void quant_kernel(const float* __restrict__ in, int R, int C, int ldq,
                             const unsigned* __restrict__ slot, float sign,
                             u16* __restrict__ qout) {
  const int segs_per_row = C >> 8;
  const int seg = blockIdx.x * 4 + (threadIdx.x >> 6);
  const int lane = threadIdx.x & 63;
  const int r = seg / segs_per_row;
  const int s = seg - r * segs_per_row;
  const float scale = fmaxf(__uint_as_float(*slot) / 7.0f, 1e-8f);
  const size_t qbase = (size_t)r * ldq + (size_t)s * 256 + lane * 4;
  int mask = 0;
  if (r < R) {
    const size_t base = (size_t)r * C + (size_t)s * 256 + lane * 4;
    float4 v = *(const float4*)(in + base);
    int q0 = quant1(v.x, scale);
    int q1 = quant1(v.y, scale);
    int q2 = quant1(v.z, scale);
    int q3 = quant1(v.w, scale);
    u16x4 o;
    o[0] = (u16)(__float_as_uint((float)q0) >> 16);
    o[1] = (u16)(__float_as_uint((float)q1) >> 16);
    o[2] = (u16)(__float_as_uint((float)q2) >> 16);
    o[3] = (u16)(__float_as_uint((float)q3) >> 16);
    *(u16x4*)(qout + qbase) = o;
    mask = q0 & q1 & q2 & q3 & 15;
  } else {
    u16x4 z = {0, 0, 0, 0};
    *(u16x4*)(qout + qbase) = z;
    mask = 0;
  }
  for (int o = 32; o > 0; o >>= 1) mask &= __shfl_xor(mask, o);
  if (lane == 0) {
    float sv = sign * (float)((mask & 7) - (mask & 8));
    qout[(size_t)r * ldq + C + s] = (u16)(__float_as_uint(sv) >> 16);
  }
  if (s == 0 && lane < (32 - segs_per_row))
    qout[(size_t)r * ldq + C + segs_per_row + lane] = 0;
}

// out = (p0+p1)+(p2+p3) (exact ints) * (s_h*s_w2) + b2
__global__ void epi2_kernel(const float* __restrict__ partial, long cstride,
                            const float* __restrict__ b2,
                            const unsigned* __restrict__ slots,
                            float* __restrict__ out, long n4) {
  const float sa = fmaxf(__uint_as_float(slots[3]) / 7.0f, 1e-8f);
  const float sb = fmaxf(__uint_as_float(slots[2]) / 7.0f, 1e-8f);
  const float sc = sa * sb;
  long i = (long)blockIdx.x * blockDim.x + threadIdx.x;
  const long stride = (long)gridDim.x * blockDim.x;
  for (; i < n4; i += stride) {
    float4 v0 = ((const float4*)partial)[i];
    float4 v1 = ((const float4*)(partial + cstride))[i];
    float4 v2 = ((const float4*)(partial + 2 * cstride))[i];
    float4 v3 = ((const float4*)(partial + 3 * cstride))[i];
    float4 bb = ((const float4*)b2)[i % 192];  // 768/4
    float4 o;
    o.x = epi_scale((v0.x + v1.x) + (v2.x + v3.x), sc, bb.x);
    o.y = epi_scale((v0.y + v1.y) + (v2.y + v3.y), sc, bb.y);
    o.z = epi_scale((v0.z + v1.z) + (v2.z + v3.z), sc, bb.z);
    o.w = epi_scale((v0.w + v1.w) + (v2.w + v3.w), sc, bb.w);
    ((float4*)out)[i] = o;
  }
}

// ---------------- GEMM -------------------------------------------------------
// 128(M) x 64(N) tile, 4 waves (2x2, each 64x32), depth-2 prefetch over 3 LDS
// buffers with counted vmcnt, XOR-swizzled LDS (pre-swizzled global source,
// linear global_load_lds dest, swizzled ds_read addr — involution, bits{4,5,6}
// masked from untouched bits{7,8,9}).
// MODE 0: epilogue scale+bias+gelu, store f32, fused absmax -> slots[3]
// MODE 1: split-K; chunk c stores exact-integer partials to outp + c*cstride.
template <int MODE>
__global__ __launch_bounds__(256) void gemm_cim(
    const u16* __restrict__ A, const u16* __restrict__ B,
    int Mstore, int ldq, int mtiles, int kbase, int krem,
    const unsigned* __restrict__ slots, int slotA, int slotB,
    const float* __restrict__ bias, float* __restrict__ outp, int ldo,
    long cstride) {
  __shared__ u16 As[3][128 * 32];  // 3 x 8KB
  __shared__ u16 Bs[3][64 * 32];   // 3 x 4KB
  const int tid = threadIdx.x;
  const int lane = tid & 63;
  const int wv = tid >> 6;

  // bijective XCD-aware swizzle (m204)
  const int nwg = gridDim.x;
  const int q8 = nwg >> 3, r8 = nwg & 7;
  const int xcd = blockIdx.x & 7, idx = blockIdx.x >> 3;
  const int sw = (xcd < r8 ? xcd * (q8 + 1) : r8 * (q8 + 1) + (xcd - r8) * q8) + idx;
  const int bm = sw % mtiles;
  const int bn = sw / mtiles;
  const long m0 = (long)bm * 128;
  const long n0 = (long)bn * 64;
  const int chunk = blockIdx.y;
  const int k_begin = chunk * kbase + min(chunk, krem);
  const int k_iters = kbase + (chunk < krem ? 1 : 0);

  const long rowb = (long)ldq * 2;
  // pre-swizzled global source: lane's linear LDS slot receives data for
  // logical slot lp (swz involution applied to the lane's 16B-slot index)
  const int lp = lane ^ ((lane >> 3) & 3) ^ (((lane >> 5) & 1) << 2);
  const int rT = wv * 16 + (lp >> 2);  // row within a 64-row chunk
  const int cbl = (lp & 3) * 16;       // byte within 64B k-slice
  const char* gA0 = (const char*)A + (m0 + rT) * rowb + (long)k_begin * 64 + cbl;
  const char* gA1 = gA0 + 64 * rowb;
  const char* gB0 = (const char*)B + (n0 + rT) * rowb + (long)k_begin * 64 + cbl;

  const int wm = wv >> 1, wn = wv & 1;
  const int lr = lane & 15, kg = lane >> 4;
  int sA[4], sB[2];
#pragma unroll
  for (int f = 0; f < 4; ++f) {
    int r = wm * 64 + f * 16 + lr;
    int s = r * 64 + kg * 16;
    s ^= ((s >> 7) & 3) << 4;
    s ^= ((s >> 9) & 1) << 6;
    sA[f] = s;
  }
#pragma unroll
  for (int f = 0; f < 2; ++f) {
    int r = wn * 32 + f * 16 + lr;
    int s = r * 64 + kg * 16;
    s ^= ((s >> 7) & 3) << 4;
    s ^= ((s >> 9) & 1) << 6;
    sB[f] = s;
  }

  f32x4 acc[4][2] = {};

#define STAGE(buf, kt) do { \
    const long kb = (long)(kt) * 64; \
    char* la = (char*)As + (buf) * 8192 + wv * 1024; \
    char* lb = (char*)Bs + (buf) * 4096 + wv * 1024; \
    GLL(gA0 + kb, la); \
    GLL(gA1 + kb, la + 4096); \
    GLL(gB0 + kb, lb); \
  } while (0)

  STAGE(0, 0);
  STAGE(1, 1);
  int cur = 0;
  for (int kt = 0; kt < k_iters; ++kt) {
    if (kt + 2 < k_iters) {
      const int nb = cur == 0 ? 2 : (cur == 1 ? 0 : 1);  // (cur+2)%3
      STAGE(nb, kt + 2);
      asm volatile("s_waitcnt vmcnt(6)" ::: "memory");  // tile kt done; kt+1,kt+2 in flight
    } else if (kt + 1 < k_iters) {
      asm volatile("s_waitcnt vmcnt(3)" ::: "memory");
    } else {
      asm volatile("s_waitcnt vmcnt(0)" ::: "memory");
    }
    __builtin_amdgcn_s_barrier();
    const char* pa = (const char*)As + cur * 8192;
    const char* pb = (const char*)Bs + cur * 4096;
    s16x8 av[4], bv[2];
#pragma unroll
    for (int f = 0; f < 4; ++f) av[f] = *(const s16x8*)(pa + sA[f]);
#pragma unroll
    for (int f = 0; f < 2; ++f) bv[f] = *(const s16x8*)(pb + sB[f]);
#pragma unroll
    for (int fa = 0; fa < 4; ++fa)
#pragma unroll
      for (int fb = 0; fb < 2; ++fb)
        acc[fa][fb] = __builtin_amdgcn_mfma_f32_16x16x32_bf16(av[fa], bv[fb], acc[fa][fb], 0, 0, 0);
    __builtin_amdgcn_s_barrier();  // all reads of `cur` done before re-stage
    cur = cur == 2 ? 0 : cur + 1;
  }
#undef STAGE

  if (MODE == 0) {
    const float sa = fmaxf(__uint_as_float(slots[slotA]) / 7.0f, 1e-8f);
    const float sb = fmaxf(__uint_as_float(slots[slotB]) / 7.0f, 1e-8f);
    const float sc = sa * sb;
    float hmax = 0.0f;
#pragma unroll
    for (int fa = 0; fa < 4; ++fa) {
#pragma unroll
      for (int rr = 0; rr < 4; ++rr) {
        const long m = m0 + wm * 64 + fa * 16 + kg * 4 + rr;  // row=(lane>>4)*4+reg
        if (m < Mstore) {
#pragma unroll
          for (int fb = 0; fb < 2; ++fb) {
            const long n = n0 + wn * 32 + fb * 16 + lr;       // col=lane&15
            float v = epi_scale(acc[fa][fb][rr], sc, bias[n]);
            v = gelu_exact(v);
            outp[m * (long)ldo + n] = v;
            hmax = fmaxf(hmax, fabsf(v));
          }
        }
      }
    }
    for (int o = 32; o > 0; o >>= 1) hmax = fmaxf(hmax, __shfl_xor(hmax, o));
    if (lane == 0) atomicMax((unsigned*)slots + 3, __float_as_uint(hmax));
  } else {
    float* po = outp + (long)chunk * cstride;
#pragma unroll
    for (int fa = 0; fa < 4; ++fa) {
#pragma unroll
      for (int rr = 0; rr < 4; ++rr) {
        const long m = m0 + wm * 64 + fa * 16 + kg * 4 + rr;
        if (m < Mstore) {
#pragma unroll
          for (int fb = 0; fb < 2; ++fb) {
            const long n = n0 + wn * 32 + fb * 16 + lr;
            po[m * (long)ldo + n] = acc[fa][fb][rr];  // exact integer partial
          }
        }
      }
    }
  }
}

// ---------------- launch -----------------------------------------------------

extern "C" void kernel_launch(void* const* d_in, const int* in_sizes, int n_in,
                              void* d_out, int out_size, void* d_ws, size_t ws_size,
                              hipStream_t stream) {
  const float* x  = (const float*)d_in[0];
  const float* w1 = (const float*)d_in[1];
  const float* b1 = (const float*)d_in[2];
  const float* w2 = (const float*)d_in[3];
  const float* b2 = (const float*)d_in[4];
  float* out = (float*)d_out;

  const int Ntok = 16 * 197;  // 3152
  const int Mpad = 3200;      // 25 tiles of 128
  const int D = 768, H = 3072;
  const int ldq1 = D + 32;    // 800  -> 25 k-iters
  const int ldq2 = H + 32;    // 3104 -> 97 k-iters

  char* ws = (char*)d_ws;
  size_t o = 0;
  unsigned* slots = (unsigned*)(ws + o); o += 256;  // [x, w1, w2, h]
  u16* xq  = (u16*)(ws + o); o += (size_t)Mpad * ldq1 * 2;
  u16* wq1 = (u16*)(ws + o); o += (size_t)H * ldq1 * 2;
  u16* wq2 = (u16*)(ws + o); o += (size_t)D * ldq2 * 2;
  u16* hq  = (u16*)(ws + o); o += (size_t)Mpad * ldq2 * 2;
  // hbuf (f32 h) and the 4 split-K partial buffers are never live at the same
  // time: union them. 4 * Ntok*D == Ntok*H exactly.
  float* hbuf = (float*)(ws + o);
  float* partial = (float*)(ws + o); o += (size_t)Ntok * H * 4;
  (void)ws_size; (void)in_sizes; (void)n_in; (void)out_size;

  hipLaunchKernelGGL(init_kernel, dim3(1), dim3(64), 0, stream, slots);

  hipLaunchKernelGGL(absmax3, dim3(512, 3), dim3(256), 0, stream,
                     x, (long)Ntok * D / 4, w1, (long)H * D / 4,
                     w2, (long)D * H / 4, slots);

  hipLaunchKernelGGL(quant_kernel, dim3(Mpad * (D / 256) / 4), dim3(256), 0, stream,
                     x, Ntok, D, ldq1, slots + 0, 1.0f, xq);
  hipLaunchKernelGGL(quant_kernel, dim3(H * (D / 256) / 4), dim3(256), 0, stream,
                     w1, H, D, ldq1, slots + 1, -1.0f, wq1);
  hipLaunchKernelGGL(quant_kernel, dim3(D * (H / 256) / 4), dim3(256), 0, stream,
                     w2, D, H, ldq2, slots + 2, -1.0f, wq2);

  // layer 1: h = gelu(cim(x,w1) + b1), fused absmax(h) -> slots[3]
  hipLaunchKernelGGL((gemm_cim<0>), dim3(25 * (H / 64), 1), dim3(256), 0, stream,
                     xq, wq1, Ntok, ldq1, 25, ldq1 / 32, 0,
                     slots, 0, 1, b1, hbuf, H, 0L);

  hipLaunchKernelGGL(quant_kernel, dim3(Mpad * (H / 256) / 4), dim3(256), 0, stream,
                     hbuf, Ntok, H, ldq2, slots + 3, 1.0f, hq);

  // layer 2: split-K x4, private exact-integer partial buffers (alias hbuf)
  hipLaunchKernelGGL((gemm_cim<1>), dim3(25 * (D / 64), 4), dim3(256), 0, stream,
                     hq, wq2, Ntok, ldq2, 25, (ldq2 / 32) / 4, (ldq2 / 32) % 4,
                     slots, 3, 2, nullptr, partial, D, (long)Ntok * D);

  hipLaunchKernelGGL(epi2_kernel, dim3(1024), dim3(256), 0, stream,
                     partial, (long)Ntok * D, b2, slots, out, (long)Ntok * D / 4);
}

// Round 4
// 218.861 us; speedup vs baseline: 1.1700x; 1.1700x over previous
//
#include <hip/hip_runtime.h>
#include <hip/hip_bf16.h>
#include <stdint.h>

typedef unsigned short u16;
typedef short s16x8 __attribute__((ext_vector_type(8)));
typedef float f32x4 __attribute__((ext_vector_type(4)));
typedef unsigned short u16x4 __attribute__((ext_vector_type(4)));

#define GLL(gp, lp) __builtin_amdgcn_global_load_lds( \
    (const __attribute__((address_space(1))) void*)(gp), \
    (__attribute__((address_space(3))) void*)(lp), 16, 0, 0)

// ---------------- exact-math helpers (match XLA/np f32 semantics) -----------

__device__ __forceinline__ float xla_erf(float x) {
#pragma clang fp contract(off)
  x = fminf(3.832506856900711f, fmaxf(-3.832506856900711f, x));
  float x2 = x * x;
  float p = -2.72614225801306e-10f;
  p = p * x2 + 2.77068142495902e-08f;
  p = p * x2 + -2.10102402082508e-06f;
  p = p * x2 + -5.69250639462346e-05f;
  p = p * x2 + -7.34990630326855e-04f;
  p = p * x2 + -2.95459980854025e-03f;
  p = p * x2 + -1.60960333262415e-02f;
  p = x * p;
  float q = -1.45660718464996e-05f;
  q = q * x2 + -2.13374055278905e-04f;
  q = q * x2 + -1.68282697438203e-03f;
  q = q * x2 + -7.37332916720468e-03f;
  q = q * x2 + -1.42647390514189e-02f;
  return p / q;
}

__device__ __forceinline__ float gelu_exact(float x) {
#pragma clang fp contract(off)
  float t = x / 1.41421356237309504880f;
  float e = xla_erf(t);
  float u = e + 1.0f;
  float v = x * u;
  return v * 0.5f;
}

__device__ __forceinline__ float epi_scale(float iacc, float sc, float b) {
#pragma clang fp contract(off)
  float v = iacc * sc;
  v = v + b;
  return v;
}

__device__ __forceinline__ int quant1(float x, float scale) {
#pragma clang fp contract(off)
  float t = x / scale;
  t = rintf(t);
  t = fmaxf(-8.0f, fminf(7.0f, t));
  return (int)t;
}

// ---------------- small kernels ---------------------------------------------

__global__ void init_kernel(unsigned* slots) {
  if (threadIdx.x < 4) slots[threadIdx.x] = 0u;
}

__global__ void absmax3(const float* __restrict__ p0, long n0,
                        const float* __restrict__ p1, long n1,
                        const float* __restrict__ p2, long n2,
                        unsigned* __restrict__ slots) {
  const int t = blockIdx.y;
  const float4* p = (const float4*)(t == 0 ? p0 : (t == 1 ? p1 : p2));
  const long n4 = (t == 0 ? n0 : (t == 1 ? n1 : n2));
  float m = 0.0f;
  long i = (long)blockIdx.x * blockDim.x + threadIdx.x;
  const long stride = (long)gridDim.x * blockDim.x;
  for (; i < n4; i += stride) {
    float4 v = p[i];
    m = fmaxf(m, fmaxf(fmaxf(fabsf(v.x), fabsf(v.y)), fmaxf(fabsf(v.z), fabsf(v.w))));
  }
  for (int o = 32; o > 0; o >>= 1) m = fmaxf(m, __shfl_xor(m, o));
  if ((threadIdx.x & 63) == 0) atomicMax(slots + t, __float_as_uint(m));
}

// fp32 [R][C] -> bf16-int [Rpad][ldq], ldq = C + 32; extra columns hold the
// per-segment signed AND-mask (ADC correction; sign=-1 for weights), zero-pad.
__global__ void quant_kernel(const float* __restrict__ in, int R, int C, int ldq,
                             const unsigned* __restrict__ slot, float sign,
                             u16* __restrict__ qout) {
  const int segs_per_row = C >> 8;
  const int seg = blockIdx.x * 4 + (threadIdx.x >> 6);
  const int lane = threadIdx.x & 63;
  const int r = seg / segs_per_row;
  const int s = seg - r * segs_per_row;
  const float scale = fmaxf(__uint_as_float(*slot) / 7.0f, 1e-8f);
  const size_t qbase = (size_t)r * ldq + (size_t)s * 256 + lane * 4;
  int mask = 0;
  if (r < R) {
    const size_t base = (size_t)r * C + (size_t)s * 256 + lane * 4;
    float4 v = *(const float4*)(in + base);
    int q0 = quant1(v.x, scale);
    int q1 = quant1(v.y, scale);
    int q2 = quant1(v.z, scale);
    int q3 = quant1(v.w, scale);
    u16x4 o;
    o[0] = (u16)(__float_as_uint((float)q0) >> 16);
    o[1] = (u16)(__float_as_uint((float)q1) >> 16);
    o[2] = (u16)(__float_as_uint((float)q2) >> 16);
    o[3] = (u16)(__float_as_uint((float)q3) >> 16);
    *(u16x4*)(qout + qbase) = o;
    mask = q0 & q1 & q2 & q3 & 15;
  } else {
    u16x4 z = {0, 0, 0, 0};
    *(u16x4*)(qout + qbase) = z;
    mask = 0;
  }
  for (int o = 32; o > 0; o >>= 1) mask &= __shfl_xor(mask, o);
  if (lane == 0) {
    float sv = sign * (float)((mask & 7) - (mask & 8));
    qout[(size_t)r * ldq + C + s] = (u16)(__float_as_uint(sv) >> 16);
  }
  if (s == 0 && lane < (32 - segs_per_row))
    qout[(size_t)r * ldq + C + segs_per_row + lane] = 0;
}

// out = (((p0+p1)+(p2+p3))+(p4+p5)) * (s_h*s_w2) + b2  (exact ints, any order)
__global__ void epi2_kernel(const float* __restrict__ partial, long cstride,
                            const float* __restrict__ b2,
                            const unsigned* __restrict__ slots,
                            float* __restrict__ out, long n4) {
  const float sa = fmaxf(__uint_as_float(slots[3]) / 7.0f, 1e-8f);
  const float sb = fmaxf(__uint_as_float(slots[2]) / 7.0f, 1e-8f);
  const float sc = sa * sb;
  long i = (long)blockIdx.x * blockDim.x + threadIdx.x;
  const long stride = (long)gridDim.x * blockDim.x;
  for (; i < n4; i += stride) {
    float4 v0 = ((const float4*)partial)[i];
    float4 v1 = ((const float4*)(partial + cstride))[i];
    float4 v2 = ((const float4*)(partial + 2 * cstride))[i];
    float4 v3 = ((const float4*)(partial + 3 * cstride))[i];
    float4 v4 = ((const float4*)(partial + 4 * cstride))[i];
    float4 v5 = ((const float4*)(partial + 5 * cstride))[i];
    float4 bb = ((const float4*)b2)[i % 192];  // 768/4
    float4 o;
    o.x = epi_scale(((v0.x + v1.x) + (v2.x + v3.x)) + (v4.x + v5.x), sc, bb.x);
    o.y = epi_scale(((v0.y + v1.y) + (v2.y + v3.y)) + (v4.y + v5.y), sc, bb.y);
    o.z = epi_scale(((v0.z + v1.z) + (v2.z + v3.z)) + (v4.z + v5.z), sc, bb.z);
    o.w = epi_scale(((v0.w + v1.w) + (v2.w + v3.w)) + (v4.w + v5.w), sc, bb.w);
    ((float4*)out)[i] = o;
  }
}

// ---------------- GEMM -------------------------------------------------------
// 128x128 tile, 4 waves (2x2, each 64x64), BK=32, depth-2 prefetch over 3 LDS
// buffer pairs (48KB total -> 3 blocks/CU) with counted vmcnt. LDS XOR-swizzle
// (round-3-verified: 0 bank conflicts): linear global_load_lds dest,
// pre-swizzled per-lane global source, same involution on ds_read addresses.
// MODE 0: epilogue scale+bias+gelu, store f32, fused absmax -> slots[3]
// MODE 1: split-K; chunk c stores exact-integer partials to outp + c*cstride.
template <int MODE>
__global__ __launch_bounds__(256) void gemm_cim(
    const u16* __restrict__ A, const u16* __restrict__ B,
    int Mstore, int ldq, int mtiles, int kbase, int krem,
    const unsigned* __restrict__ slots, int slotA, int slotB,
    const float* __restrict__ bias, float* __restrict__ outp, int ldo,
    long cstride) {
  __shared__ u16 As[3][128 * 32];  // 3 x 8KB
  __shared__ u16 Bs[3][128 * 32];  // 3 x 8KB
  const int tid = threadIdx.x;
  const int lane = tid & 63;
  const int wv = tid >> 6;

  // bijective XCD-aware swizzle (m204)
  const int nwg = gridDim.x;
  const int q8 = nwg >> 3, r8 = nwg & 7;
  const int xcd = blockIdx.x & 7, idx = blockIdx.x >> 3;
  const int sw = (xcd < r8 ? xcd * (q8 + 1) : r8 * (q8 + 1) + (xcd - r8) * q8) + idx;
  const int bm = sw % mtiles;
  const int bn = sw / mtiles;
  const long m0 = (long)bm * 128;
  const long n0 = (long)bn * 128;
  const int chunk = blockIdx.y;
  const int k_begin = chunk * kbase + min(chunk, krem);
  const int k_iters = kbase + (chunk < krem ? 1 : 0);

  const long rowb = (long)ldq * 2;
  // pre-swizzled global source lane permutation (involution, round-3-verified)
  const int lp = lane ^ ((lane >> 3) & 3) ^ (((lane >> 5) & 1) << 2);
  const int rT = wv * 16 + (lp >> 2);  // row within a 64-row chunk
  const int cbl = (lp & 3) * 16;       // byte within 64B k-slice
  const char* gA0 = (const char*)A + (m0 + rT) * rowb + (long)k_begin * 64 + cbl;
  const char* gA1 = gA0 + 64 * rowb;
  const char* gB0 = (const char*)B + (n0 + rT) * rowb + (long)k_begin * 64 + cbl;
  const char* gB1 = gB0 + 64 * rowb;

  const int wm = wv >> 1, wn = wv & 1;
  const int lr = lane & 15, kg = lane >> 4;
  int sA[4], sB[4];
#pragma unroll
  for (int f = 0; f < 4; ++f) {
    int r = wm * 64 + f * 16 + lr;
    int s = r * 64 + kg * 16;
    s ^= ((s >> 7) & 3) << 4;
    s ^= ((s >> 9) & 1) << 6;
    sA[f] = s;
    r = wn * 64 + f * 16 + lr;
    s = r * 64 + kg * 16;
    s ^= ((s >> 7) & 3) << 4;
    s ^= ((s >> 9) & 1) << 6;
    sB[f] = s;
  }

  f32x4 acc[4][4] = {};

#define STAGE(buf, kt) do { \
    const long kb = (long)(kt) * 64; \
    char* la = (char*)As + (buf) * 8192 + wv * 1024; \
    char* lb = (char*)Bs + (buf) * 8192 + wv * 1024; \
    GLL(gA0 + kb, la); \
    GLL(gA1 + kb, la + 4096); \
    GLL(gB0 + kb, lb); \
    GLL(gB1 + kb, lb + 4096); \
  } while (0)

  STAGE(0, 0);
  STAGE(1, 1);
  int cur = 0;
  for (int kt = 0; kt < k_iters; ++kt) {
    if (kt + 2 < k_iters) {
      const int nb = cur == 0 ? 2 : (cur == 1 ? 0 : 1);  // (cur+2)%3
      STAGE(nb, kt + 2);
      asm volatile("s_waitcnt vmcnt(8)" ::: "memory");  // tile kt landed
    } else if (kt + 1 < k_iters) {
      asm volatile("s_waitcnt vmcnt(4)" ::: "memory");
    } else {
      asm volatile("s_waitcnt vmcnt(0)" ::: "memory");
    }
    __builtin_amdgcn_s_barrier();
    const char* pa = (const char*)As + cur * 8192;
    const char* pb = (const char*)Bs + cur * 8192;
    s16x8 av[4], bv[4];
#pragma unroll
    for (int f = 0; f < 4; ++f) av[f] = *(const s16x8*)(pa + sA[f]);
#pragma unroll
    for (int f = 0; f < 4; ++f) bv[f] = *(const s16x8*)(pb + sB[f]);
#pragma unroll
    for (int fa = 0; fa < 4; ++fa)
#pragma unroll
      for (int fb = 0; fb < 4; ++fb)
        acc[fa][fb] = __builtin_amdgcn_mfma_f32_16x16x32_bf16(av[fa], bv[fb], acc[fa][fb], 0, 0, 0);
    __builtin_amdgcn_s_barrier();  // all reads of `cur` done before re-stage
    cur = cur == 2 ? 0 : cur + 1;
  }
#undef STAGE

  if (MODE == 0) {
    const float sa = fmaxf(__uint_as_float(slots[slotA]) / 7.0f, 1e-8f);
    const float sb = fmaxf(__uint_as_float(slots[slotB]) / 7.0f, 1e-8f);
    const float sc = sa * sb;
    float hmax = 0.0f;
#pragma unroll
    for (int fa = 0; fa < 4; ++fa) {
#pragma unroll
      for (int rr = 0; rr < 4; ++rr) {
        const long m = m0 + wm * 64 + fa * 16 + kg * 4 + rr;  // row=(lane>>4)*4+reg
        if (m < Mstore) {
#pragma unroll
          for (int fb = 0; fb < 4; ++fb) {
            const long n = n0 + wn * 64 + fb * 16 + lr;       // col=lane&15
            float v = epi_scale(acc[fa][fb][rr], sc, bias[n]);
            v = gelu_exact(v);
            outp[m * (long)ldo + n] = v;
            hmax = fmaxf(hmax, fabsf(v));
          }
        }
      }
    }
    for (int o = 32; o > 0; o >>= 1) hmax = fmaxf(hmax, __shfl_xor(hmax, o));
    if (lane == 0) atomicMax((unsigned*)slots + 3, __float_as_uint(hmax));
  } else {
    float* po = outp + (long)chunk * cstride;
#pragma unroll
    for (int fa = 0; fa < 4; ++fa) {
#pragma unroll
      for (int rr = 0; rr < 4; ++rr) {
        const long m = m0 + wm * 64 + fa * 16 + kg * 4 + rr;
        if (m < Mstore) {
#pragma unroll
          for (int fb = 0; fb < 4; ++fb) {
            const long n = n0 + wn * 64 + fb * 16 + lr;
            po[m * (long)ldo + n] = acc[fa][fb][rr];  // exact integer partial
          }
        }
      }
    }
  }
}

// ---------------- launch -----------------------------------------------------

extern "C" void kernel_launch(void* const* d_in, const int* in_sizes, int n_in,
                              void* d_out, int out_size, void* d_ws, size_t ws_size,
                              hipStream_t stream) {
  const float* x  = (const float*)d_in[0];
  const float* w1 = (const float*)d_in[1];
  const float* b1 = (const float*)d_in[2];
  const float* w2 = (const float*)d_in[3];
  const float* b2 = (const float*)d_in[4];
  float* out = (float*)d_out;

  const int Ntok = 16 * 197;  // 3152
  const int Mpad = 3200;      // 25 tiles of 128
  const int D = 768, H = 3072;
  const int ldq1 = D + 32;    // 800  -> 25 k-iters
  const int ldq2 = H + 32;    // 3104 -> 97 k-iters
  const int SPLITK = 6;       // 97 = 6*16 + 1 -> kbase=16, krem=1

  char* ws = (char*)d_ws;
  size_t o = 0;
  unsigned* slots = (unsigned*)(ws + o); o += 256;  // [x, w1, w2, h]
  u16* xq  = (u16*)(ws + o); o += (size_t)Mpad * ldq1 * 2;
  u16* wq1 = (u16*)(ws + o); o += (size_t)H * ldq1 * 2;
  u16* wq2 = (u16*)(ws + o); o += (size_t)D * ldq2 * 2;
  u16* hq  = (u16*)(ws + o); o += (size_t)Mpad * ldq2 * 2;
  // hbuf (f32 h, 38.7MB) and the 6 split-K partial buffers (58.1MB) are never
  // live simultaneously: union them.
  float* hbuf = (float*)(ws + o);
  float* partial = (float*)(ws + o); o += (size_t)SPLITK * Ntok * D * 4;
  (void)ws_size; (void)in_sizes; (void)n_in; (void)out_size;

  hipLaunchKernelGGL(init_kernel, dim3(1), dim3(64), 0, stream, slots);

  hipLaunchKernelGGL(absmax3, dim3(512, 3), dim3(256), 0, stream,
                     x, (long)Ntok * D / 4, w1, (long)H * D / 4,
                     w2, (long)D * H / 4, slots);

  hipLaunchKernelGGL(quant_kernel, dim3(Mpad * (D / 256) / 4), dim3(256), 0, stream,
                     x, Ntok, D, ldq1, slots + 0, 1.0f, xq);
  hipLaunchKernelGGL(quant_kernel, dim3(H * (D / 256) / 4), dim3(256), 0, stream,
                     w1, H, D, ldq1, slots + 1, -1.0f, wq1);
  hipLaunchKernelGGL(quant_kernel, dim3(D * (H / 256) / 4), dim3(256), 0, stream,
                     w2, D, H, ldq2, slots + 2, -1.0f, wq2);

  // layer 1: h = gelu(cim(x,w1) + b1), fused absmax(h) -> slots[3]
  hipLaunchKernelGGL((gemm_cim<0>), dim3(25 * (H / 128), 1), dim3(256), 0, stream,
                     xq, wq1, Ntok, ldq1, 25, ldq1 / 32, 0,
                     slots, 0, 1, b1, hbuf, H, 0L);

  hipLaunchKernelGGL(quant_kernel, dim3(Mpad * (H / 256) / 4), dim3(256), 0, stream,
                     hbuf, Ntok, H, ldq2, slots + 3, 1.0f, hq);

  // layer 2: split-K x6, private exact-integer partial buffers (union w/ hbuf)
  hipLaunchKernelGGL((gemm_cim<1>), dim3(25 * (D / 128), SPLITK), dim3(256), 0, stream,
                     hq, wq2, Ntok, ldq2, 25, (ldq2 / 32) / SPLITK, (ldq2 / 32) % SPLITK,
                     slots, 3, 2, nullptr, partial, D, (long)Ntok * D);

  hipLaunchKernelGGL(epi2_kernel, dim3(1024), dim3(256), 0, stream,
                     partial, (long)Ntok * D, b2, slots, out, (long)Ntok * D / 4);
}

// Round 5
// 196.252 us; speedup vs baseline: 1.3048x; 1.1152x over previous
//
#include <hip/hip_runtime.h>
#include <hip/hip_bf16.h>
#include <stdint.h>

typedef unsigned short u16;
typedef int i32x4 __attribute__((ext_vector_type(4)));

#define GLL(gp, lp) __builtin_amdgcn_global_load_lds( \
    (const __attribute__((address_space(1))) void*)(gp), \
    (__attribute__((address_space(3))) void*)(lp), 16, 0, 0)

// ---------------- exact-math helpers (match XLA/np f32 semantics) -----------

__device__ __forceinline__ float xla_erf(float x) {
#pragma clang fp contract(off)
  x = fminf(3.832506856900711f, fmaxf(-3.832506856900711f, x));
  float x2 = x * x;
  float p = -2.72614225801306e-10f;
  p = p * x2 + 2.77068142495902e-08f;
  p = p * x2 + -2.10102402082508e-06f;
  p = p * x2 + -5.69250639462346e-05f;
  p = p * x2 + -7.34990630326855e-04f;
  p = p * x2 + -2.95459980854025e-03f;
  p = p * x2 + -1.60960333262415e-02f;
  p = x * p;
  float q = -1.45660718464996e-05f;
  q = q * x2 + -2.13374055278905e-04f;
  q = q * x2 + -1.68282697438203e-03f;
  q = q * x2 + -7.37332916720468e-03f;
  q = q * x2 + -1.42647390514189e-02f;
  return p / q;
}

__device__ __forceinline__ float gelu_exact(float x) {
#pragma clang fp contract(off)
  float t = x / 1.41421356237309504880f;
  float e = xla_erf(t);
  float u = e + 1.0f;
  float v = x * u;
  return v * 0.5f;
}

__device__ __forceinline__ float epi_scale(float iacc, float sc, float b) {
#pragma clang fp contract(off)
  float v = iacc * sc;
  v = v + b;
  return v;
}

__device__ __forceinline__ int quant1(float x, float scale) {
#pragma clang fp contract(off)
  float t = x / scale;
  t = rintf(t);
  t = fmaxf(-8.0f, fminf(7.0f, t));
  return (int)t;
}

// ---------------- small kernels ---------------------------------------------

__global__ void init_kernel(unsigned* slots) {
  if (threadIdx.x < 4) slots[threadIdx.x] = 0u;
}

__global__ void absmax3(const float* __restrict__ p0, long n0,
                        const float* __restrict__ p1, long n1,
                        const float* __restrict__ p2, long n2,
                        unsigned* __restrict__ slots) {
  const int t = blockIdx.y;
  const float4* p = (const float4*)(t == 0 ? p0 : (t == 1 ? p1 : p2));
  const long n4 = (t == 0 ? n0 : (t == 1 ? n1 : n2));
  float m = 0.0f;
  long i = (long)blockIdx.x * blockDim.x + threadIdx.x;
  const long stride = (long)gridDim.x * blockDim.x;
  for (; i < n4; i += stride) {
    float4 v = p[i];
    m = fmaxf(m, fmaxf(fmaxf(fabsf(v.x), fabsf(v.y)), fmaxf(fabsf(v.z), fabsf(v.w))));
  }
  for (int o = 32; o > 0; o >>= 1) m = fmaxf(m, __shfl_xor(m, o));
  if ((threadIdx.x & 63) == 0) atomicMax(slots + t, __float_as_uint(m));
}

// fp32 [R][C] -> signed i8 [Rpad][ldq] (row stride ldq bytes, 64-aligned);
// bytes [C, C+segs) hold the per-segment signed AND-mask (ADC correction,
// sign=-1 for weights); [C+segs, ldq) zero. Padded rows fully zero.
__global__ void quant_kernel(const float* __restrict__ in, int R, int C, int ldq,
                             const unsigned* __restrict__ slot, int sign,
                             char* __restrict__ qout) {
  const int segs_per_row = C >> 8;
  const int seg = blockIdx.x * 4 + (threadIdx.x >> 6);
  const int lane = threadIdx.x & 63;
  const int r = seg / segs_per_row;
  const int s = seg - r * segs_per_row;
  const float scale = fmaxf(__uint_as_float(*slot) / 7.0f, 1e-8f);
  const size_t qbase = (size_t)r * ldq + (size_t)s * 256 + lane * 4;
  int mask = 0;
  if (r < R) {
    const size_t base = (size_t)r * C + (size_t)s * 256 + lane * 4;
    float4 v = *(const float4*)(in + base);
    int q0 = quant1(v.x, scale);
    int q1 = quant1(v.y, scale);
    int q2 = quant1(v.z, scale);
    int q3 = quant1(v.w, scale);
    unsigned pk = (q0 & 0xff) | ((q1 & 0xff) << 8) | ((q2 & 0xff) << 16) |
                  ((unsigned)(q3 & 0xff) << 24);
    *(unsigned*)(qout + qbase) = pk;
    mask = q0 & q1 & q2 & q3 & 15;
  } else {
    *(unsigned*)(qout + qbase) = 0u;
    mask = 0;
  }
  for (int o = 32; o > 0; o >>= 1) mask &= __shfl_xor(mask, o);
  if (lane == 0)
    qout[(size_t)r * ldq + C + s] = (char)(sign * ((mask & 7) - (mask & 8)));
  const int padw = ldq - C - segs_per_row;
  if (s == 0 && lane < padw)
    qout[(size_t)r * ldq + C + segs_per_row + lane] = 0;
}

// out = (((p0+p1)+(p2+p3))+(p4+p5)) * (s_h*s_w2) + b2  (exact ints, any order)
__global__ void epi2_kernel(const float* __restrict__ partial, long cstride,
                            const float* __restrict__ b2,
                            const unsigned* __restrict__ slots,
                            float* __restrict__ out, long n4) {
  const float sa = fmaxf(__uint_as_float(slots[3]) / 7.0f, 1e-8f);
  const float sb = fmaxf(__uint_as_float(slots[2]) / 7.0f, 1e-8f);
  const float sc = sa * sb;
  long i = (long)blockIdx.x * blockDim.x + threadIdx.x;
  const long stride = (long)gridDim.x * blockDim.x;
  for (; i < n4; i += stride) {
    float4 v0 = ((const float4*)partial)[i];
    float4 v1 = ((const float4*)(partial + cstride))[i];
    float4 v2 = ((const float4*)(partial + 2 * cstride))[i];
    float4 v3 = ((const float4*)(partial + 3 * cstride))[i];
    float4 v4 = ((const float4*)(partial + 4 * cstride))[i];
    float4 v5 = ((const float4*)(partial + 5 * cstride))[i];
    float4 bb = ((const float4*)b2)[i % 192];  // 768/4
    float4 o;
    o.x = epi_scale(((v0.x + v1.x) + (v2.x + v3.x)) + (v4.x + v5.x), sc, bb.x);
    o.y = epi_scale(((v0.y + v1.y) + (v2.y + v3.y)) + (v4.y + v5.y), sc, bb.y);
    o.z = epi_scale(((v0.z + v1.z) + (v2.z + v3.z)) + (v4.z + v5.z), sc, bb.z);
    o.w = epi_scale(((v0.w + v1.w) + (v2.w + v3.w)) + (v4.w + v5.w), sc, bb.w);
    ((float4*)out)[i] = o;
  }
}

// ---------------- GEMM (i8, exact) -------------------------------------------
// 128x128 tile, 4 waves (2x2, each 64x64), BK=64 i8, mfma_i32_16x16x64_i8
// (i32 accumulate — exact). Depth-2 prefetch over 3 LDS buffer pairs (24KB)
// with counted vmcnt. LDS tile is [128 rows][64B] — byte-identical geometry to
// the round-3-verified XOR swizzle (0 bank conflicts): linear GLL dest,
// pre-swizzled per-lane global source, same involution on ds_read addresses.
// MODE 0: epilogue scale+bias+gelu, store f32, fused absmax -> slots[3]
// MODE 1: split-K; chunk c stores exact-integer partials (as f32) per chunk.
template <int MODE>
__global__ __launch_bounds__(256) void gemm_cim(
    const char* __restrict__ A, const char* __restrict__ B,
    int Mstore, int ldq, int mtiles, int kbase, int krem,
    const unsigned* __restrict__ slots, int slotA, int slotB,
    const float* __restrict__ bias, float* __restrict__ outp, int ldo,
    long cstride) {
  __shared__ char As[3][128 * 64];  // 3 x 8KB
  __shared__ char Bs[3][128 * 64];  // 3 x 8KB
  const int tid = threadIdx.x;
  const int lane = tid & 63;
  const int wv = tid >> 6;

  // bijective XCD-aware swizzle (m204)
  const int nwg = gridDim.x;
  const int q8 = nwg >> 3, r8 = nwg & 7;
  const int xcd = blockIdx.x & 7, idx = blockIdx.x >> 3;
  const int sw = (xcd < r8 ? xcd * (q8 + 1) : r8 * (q8 + 1) + (xcd - r8) * q8) + idx;
  const int bm = sw % mtiles;
  const int bn = sw / mtiles;
  const long m0 = (long)bm * 128;
  const long n0 = (long)bn * 128;
  const int chunk = blockIdx.y;
  const int k_begin = chunk * kbase + min(chunk, krem);   // in BK=64 units
  const int k_iters = kbase + (chunk < krem ? 1 : 0);

  const long rowb = (long)ldq;  // bytes per row (i8)
  // pre-swizzled global source lane permutation (involution, round-3-verified)
  const int lp = lane ^ ((lane >> 3) & 3) ^ (((lane >> 5) & 1) << 2);
  const int rT = wv * 16 + (lp >> 2);  // row within a 64-row chunk
  const int cbl = (lp & 3) * 16;       // byte within 64B k-slice
  const char* gA0 = A + (m0 + rT) * rowb + (long)k_begin * 64 + cbl;
  const char* gA1 = gA0 + 64 * rowb;
  const char* gB0 = B + (n0 + rT) * rowb + (long)k_begin * 64 + cbl;
  const char* gB1 = gB0 + 64 * rowb;

  const int wm = wv >> 1, wn = wv & 1;
  const int lr = lane & 15, kg = lane >> 4;
  int sA[4], sB[4];
#pragma unroll
  for (int f = 0; f < 4; ++f) {
    int r = wm * 64 + f * 16 + lr;
    int s = r * 64 + kg * 16;
    s ^= ((s >> 7) & 3) << 4;
    s ^= ((s >> 9) & 1) << 6;
    sA[f] = s;
    r = wn * 64 + f * 16 + lr;
    s = r * 64 + kg * 16;
    s ^= ((s >> 7) & 3) << 4;
    s ^= ((s >> 9) & 1) << 6;
    sB[f] = s;
  }

  i32x4 acc[4][4] = {};

#define STAGE(buf, kt) do { \
    const long kb = (long)(kt) * 64; \
    char* la = (char*)As + (buf) * 8192 + wv * 1024; \
    char* lb = (char*)Bs + (buf) * 8192 + wv * 1024; \
    GLL(gA0 + kb, la); \
    GLL(gA1 + kb, la + 4096); \
    GLL(gB0 + kb, lb); \
    GLL(gB1 + kb, lb + 4096); \
  } while (0)

  STAGE(0, 0);
  STAGE(1, 1);
  int cur = 0;
  for (int kt = 0; kt < k_iters; ++kt) {
    if (kt + 2 < k_iters) {
      const int nb = cur == 0 ? 2 : (cur == 1 ? 0 : 1);  // (cur+2)%3
      STAGE(nb, kt + 2);
      asm volatile("s_waitcnt vmcnt(8)" ::: "memory");  // tile kt landed
    } else if (kt + 1 < k_iters) {
      asm volatile("s_waitcnt vmcnt(4)" ::: "memory");
    } else {
      asm volatile("s_waitcnt vmcnt(0)" ::: "memory");
    }
    __builtin_amdgcn_s_barrier();
    const char* pa = (const char*)As + cur * 8192;
    const char* pb = (const char*)Bs + cur * 8192;
    i32x4 av[4], bv[4];
#pragma unroll
    for (int f = 0; f < 4; ++f) av[f] = *(const i32x4*)(pa + sA[f]);
#pragma unroll
    for (int f = 0; f < 4; ++f) bv[f] = *(const i32x4*)(pb + sB[f]);
#pragma unroll
    for (int fa = 0; fa < 4; ++fa)
#pragma unroll
      for (int fb = 0; fb < 4; ++fb)
        acc[fa][fb] = __builtin_amdgcn_mfma_i32_16x16x64_i8(av[fa], bv[fb], acc[fa][fb], 0, 0, 0);
    __builtin_amdgcn_s_barrier();  // all reads of `cur` done before re-stage
    cur = cur == 2 ? 0 : cur + 1;
  }
#undef STAGE

  if (MODE == 0) {
    const float sa = fmaxf(__uint_as_float(slots[slotA]) / 7.0f, 1e-8f);
    const float sb = fmaxf(__uint_as_float(slots[slotB]) / 7.0f, 1e-8f);
    const float sc = sa * sb;
    float hmax = 0.0f;
#pragma unroll
    for (int fa = 0; fa < 4; ++fa) {
#pragma unroll
      for (int rr = 0; rr < 4; ++rr) {
        const long m = m0 + wm * 64 + fa * 16 + kg * 4 + rr;  // row=(lane>>4)*4+reg
        if (m < Mstore) {
#pragma unroll
          for (int fb = 0; fb < 4; ++fb) {
            const long n = n0 + wn * 64 + fb * 16 + lr;       // col=lane&15
            float v = epi_scale((float)acc[fa][fb][rr], sc, bias[n]);
            v = gelu_exact(v);
            outp[m * (long)ldo + n] = v;
            hmax = fmaxf(hmax, fabsf(v));
          }
        }
      }
    }
    for (int o = 32; o > 0; o >>= 1) hmax = fmaxf(hmax, __shfl_xor(hmax, o));
    if (lane == 0) atomicMax((unsigned*)slots + 3, __float_as_uint(hmax));
  } else {
    float* po = outp + (long)chunk * cstride;
#pragma unroll
    for (int fa = 0; fa < 4; ++fa) {
#pragma unroll
      for (int rr = 0; rr < 4; ++rr) {
        const long m = m0 + wm * 64 + fa * 16 + kg * 4 + rr;
        if (m < Mstore) {
#pragma unroll
          for (int fb = 0; fb < 4; ++fb) {
            const long n = n0 + wn * 64 + fb * 16 + lr;
            po[m * (long)ldo + n] = (float)acc[fa][fb][rr];  // exact ints
          }
        }
      }
    }
  }
}

// ---------------- launch -----------------------------------------------------

extern "C" void kernel_launch(void* const* d_in, const int* in_sizes, int n_in,
                              void* d_out, int out_size, void* d_ws, size_t ws_size,
                              hipStream_t stream) {
  const float* x  = (const float*)d_in[0];
  const float* w1 = (const float*)d_in[1];
  const float* b1 = (const float*)d_in[2];
  const float* w2 = (const float*)d_in[3];
  const float* b2 = (const float*)d_in[4];
  float* out = (float*)d_out;

  const int Ntok = 16 * 197;  // 3152
  const int Mpad = 3200;      // 25 tiles of 128
  const int D = 768, H = 3072;
  const int ldq1 = 832;       // 768 + 3 corr + pad -> 13 BK=64 iters, 64-aligned
  const int ldq2 = 3136;      // 3072 + 12 corr + pad -> 49 iters
  const int SPLITK = 6;       // 49 = 6*8 + 1 -> kbase=8, krem=1

  char* ws = (char*)d_ws;
  size_t o = 0;
  unsigned* slots = (unsigned*)(ws + o); o += 256;  // [x, w1, w2, h]
  char* xq  = ws + o; o += (size_t)Mpad * ldq1;
  char* wq1 = ws + o; o += (size_t)H * ldq1;
  char* wq2 = ws + o; o += (size_t)D * ldq2;
  char* hq  = ws + o; o += (size_t)Mpad * ldq2;
  o = (o + 255) & ~(size_t)255;
  // hbuf (f32 h, 38.7MB) and the 6 split-K partial buffers (58.1MB) are never
  // live simultaneously: union them.
  float* hbuf = (float*)(ws + o);
  float* partial = (float*)(ws + o); o += (size_t)SPLITK * Ntok * D * 4;
  (void)ws_size; (void)in_sizes; (void)n_in; (void)out_size;

  hipLaunchKernelGGL(init_kernel, dim3(1), dim3(64), 0, stream, slots);

  hipLaunchKernelGGL(absmax3, dim3(512, 3), dim3(256), 0, stream,
                     x, (long)Ntok * D / 4, w1, (long)H * D / 4,
                     w2, (long)D * H / 4, slots);

  hipLaunchKernelGGL(quant_kernel, dim3(Mpad * (D / 256) / 4), dim3(256), 0, stream,
                     x, Ntok, D, ldq1, slots + 0, 1, xq);
  hipLaunchKernelGGL(quant_kernel, dim3(H * (D / 256) / 4), dim3(256), 0, stream,
                     w1, H, D, ldq1, slots + 1, -1, wq1);
  hipLaunchKernelGGL(quant_kernel, dim3(D * (H / 256) / 4), dim3(256), 0, stream,
                     w2, D, H, ldq2, slots + 2, -1, wq2);

  // layer 1: h = gelu(cim(x,w1) + b1), fused absmax(h) -> slots[3]
  hipLaunchKernelGGL((gemm_cim<0>), dim3(25 * (H / 128), 1), dim3(256), 0, stream,
                     xq, wq1, Ntok, ldq1, 25, ldq1 / 64, 0,
                     slots, 0, 1, b1, hbuf, H, 0L);

  hipLaunchKernelGGL(quant_kernel, dim3(Mpad * (H / 256) / 4), dim3(256), 0, stream,
                     hbuf, Ntok, H, ldq2, slots + 3, 1, hq);

  // layer 2: split-K x6, private exact-integer partial buffers (union w/ hbuf)
  hipLaunchKernelGGL((gemm_cim<1>), dim3(25 * (D / 128), SPLITK), dim3(256), 0, stream,
                     hq, wq2, Ntok, ldq2, 25, (ldq2 / 64) / SPLITK, (ldq2 / 64) % SPLITK,
                     slots, 3, 2, nullptr, partial, D, (long)Ntok * D);

  hipLaunchKernelGGL(epi2_kernel, dim3(1024), dim3(256), 0, stream,
                     partial, (long)Ntok * D, b2, slots, out, (long)Ntok * D / 4);
}